// Round 5
// baseline (737.504 us; speedup 1.0000x reference)
//
#include <hip/hip_runtime.h>

#define EPSV 0.001f
#define NCTX 16
#define DIM  64
#define NSLICE 16
#define PART_STRIDE 2080   // floats per partial block: s1[1024] s2[1024] cnt[16] pad
#define P2_STRIDE   132    // per (ctx,slice): s1[64] s2[64] cnt[1] pad

// ws layout (floats): [0,1024) scale; [1024,2048) shift;
// [2048, 2048+nb*PART_STRIDE) stage-1 partials; then 16*16*P2_STRIDE stage-2.
#define WS_SCALE 0
#define WS_SHIFT 1024
#define WS_PART  2048

typedef float v4f __attribute__((ext_vector_type(4)));

// ---------------- Pass 1: ds_add_f32 shared accumulation ----------------
// One 8 KB accumulator per block (s1[16][64], s2[16][64]); per row each lane
// issues two fire-and-forget LDS fp atomics (native ds_add_f32, no RMW
// dependency chain, no lgkmcnt stall). Counts per-lane in a register:
// lane k counts rows with c==k. LDS is small -> 8 blocks/CU occupancy.
__global__ __launch_bounds__(256) void stats_kernel(
    const float* __restrict__ samples,
    const int* __restrict__ contexts,
    float* __restrict__ part, int N) {
  __shared__ float sacc[2 * NCTX * DIM];   // 8 KB: s1 [0,1024), s2 [1024,2048)
  __shared__ float cshare[4][NCTX];

  int tid  = threadIdx.x;
  int lane = tid & 63;
  int wv   = tid >> 6;

  for (int i = tid; i < 2 * NCTX * DIM; i += 256) sacc[i] = 0.f;
  __syncthreads();

  float cntk = 0.f;
  int gw   = blockIdx.x * 4 + wv;
  int nw   = gridDim.x * 4;
  int step = nw * 4;

#define STLOAD(vv, cc, r)                                                  \
  do {                                                                     \
    if ((r) < N) {                                                         \
      vv = samples[(size_t)(r) * DIM + lane];                              \
      cc = contexts[r];                                                    \
    } else { vv = 0.f; cc = -1; }                                          \
  } while (0)

#define STPROC(vv, cc)                                                     \
  do {                                                                     \
    if ((cc) >= 0) {                                                       \
      int idx = (cc) * DIM + lane;                                         \
      (void)__hip_atomic_fetch_add(&sacc[idx], (vv), __ATOMIC_RELAXED,     \
                                   __HIP_MEMORY_SCOPE_WORKGROUP);          \
      (void)__hip_atomic_fetch_add(&sacc[NCTX * DIM + idx], (vv) * (vv),   \
                                   __ATOMIC_RELAXED,                       \
                                   __HIP_MEMORY_SCOPE_WORKGROUP);          \
      cntk += (lane == (cc)) ? 1.f : 0.f;                                  \
    }                                                                      \
  } while (0)

  // 2-group-deep software pipeline (8 rows / 2 KB in flight per wave)
  float v0, v1, v2, v3, u0, u1, u2, u3;
  int   c0, c1, c2, c3, d0, d1, d2, d3;
  int row = gw;
  STLOAD(v0, c0, row);            STLOAD(v1, c1, row + nw);
  STLOAD(v2, c2, row + 2 * nw);   STLOAD(v3, c3, row + 3 * nw);
  int rowB = row + step;
  STLOAD(u0, d0, rowB);           STLOAD(u1, d1, rowB + nw);
  STLOAD(u2, d2, rowB + 2 * nw);  STLOAD(u3, d3, rowB + 3 * nw);

  while (row < N) {
    int rowC = row + 2 * step;
    float w0, w1, w2, w3;
    int   e0, e1, e2, e3;
    STLOAD(w0, e0, rowC);           STLOAD(w1, e1, rowC + nw);
    STLOAD(w2, e2, rowC + 2 * nw);  STLOAD(w3, e3, rowC + 3 * nw);

    STPROC(v0, c0); STPROC(v1, c1); STPROC(v2, c2); STPROC(v3, c3);

    v0 = u0; c0 = d0; v1 = u1; c1 = d1;
    v2 = u2; c2 = d2; v3 = u3; c3 = d3;
    u0 = w0; d0 = e0; u1 = w1; d1 = e1;
    u2 = w2; d2 = e2; u3 = w3; d3 = e3;
    row += step;
  }
#undef STLOAD
#undef STPROC

  __syncthreads();

  // writeout (sacc layout already matches pb: s1 then s2)
  float* pb = part + (size_t)blockIdx.x * PART_STRIDE;
  for (int i = tid; i < 2 * NCTX * DIM; i += 256) pb[i] = sacc[i];
  if (lane < NCTX) cshare[wv][lane] = cntk;
  __syncthreads();
  if (tid < NCTX)
    pb[2048 + tid] = cshare[0][tid] + cshare[1][tid] +
                     cshare[2][tid] + cshare[3][tid];
}

// ------------- Pass 2a: tree-reduce partials (all CUs active) -------------
__global__ __launch_bounds__(256) void reduce_a_kernel(
    const float* __restrict__ part, float* __restrict__ part2, int nb) {
  int c     = blockIdx.x & (NCTX - 1);
  int slice = blockIdx.x >> 4;
  int tid = threadIdx.x, d = tid & 63, g = tid >> 6;
  int per = nb / NSLICE;
  int b0  = slice * per;

  float a1 = 0.f, a2 = 0.f, ac = 0.f;
  float b1 = 0.f, b2 = 0.f, bc = 0.f;
  for (int b = b0 + g; b < b0 + per; b += 8) {
    const float* p = part + (size_t)b * PART_STRIDE;
    a1 += p[c * DIM + d];
    a2 += p[1024 + c * DIM + d];
    if (d == 0) ac += p[2048 + c];
    int bb = b + 4;
    if (bb < b0 + per) {
      const float* q = part + (size_t)bb * PART_STRIDE;
      b1 += q[c * DIM + d];
      b2 += q[1024 + c * DIM + d];
      if (d == 0) bc += q[2048 + c];
    }
  }
  a1 += b1; a2 += b2; ac += bc;

  __shared__ float r1[4][DIM], r2[4][DIM], rc[4];
  r1[g][d] = a1;
  r2[g][d] = a2;
  if (d == 0) rc[g] = ac;
  __syncthreads();

  if (tid < DIM) {
    float* o = part2 + (size_t)(c * NSLICE + slice) * P2_STRIDE;
    o[tid]      = r1[0][tid] + r1[1][tid] + r1[2][tid] + r1[3][tid];
    o[64 + tid] = r2[0][tid] + r2[1][tid] + r2[2][tid] + r2[3][tid];
    if (tid == 0) o[128] = rc[0] + rc[1] + rc[2] + rc[3];
  }
}

// ------------- Pass 2b: final 16-way sum + scale/shift finalize -------------
__global__ __launch_bounds__(64) void finalize_kernel(
    const float* __restrict__ part2,
    const float* __restrict__ gamma,
    const float* __restrict__ beta,
    const float* __restrict__ priors,
    float* __restrict__ ws) {
  int c = blockIdx.x;
  int d = threadIdx.x;
  float s1 = 0.f, s2 = 0.f, cnt = 0.f;
#pragma unroll
  for (int s = 0; s < NSLICE; ++s) {
    const float* p = part2 + (size_t)(c * NSLICE + s) * P2_STRIDE;
    s1  += p[d];
    s2  += p[64 + d];
    cnt += p[128];
  }
  float safe = fmaxf(cnt, 1.f);
  float mean = s1 / safe;
  float var  = s2 / safe - mean * mean;
  float istd = rsqrtf(var + EPSV);
  float ps   = rsqrtf(priors[c]);
  float gm   = gamma[c * DIM + d];
  float scale = gm * istd * ps;
  float shift = (beta[c * DIM + d] - gm * mean * istd) * ps;
  if (!(cnt > 0.f)) { scale = 1.f; shift = 0.f; }  // where(cnt>0, y, x)
  ws[WS_SCALE + c * DIM + d] = scale;
  ws[WS_SHIFT + c * DIM + d] = shift;
}

// ---------------- Pass 3: y = x * scale[c] + shift[c] ----------------
// REVERSE traversal: stats just streamed samples (244 MiB <= 256 MiB L3)
// front-to-back, so the tail is L3-resident; reading back-to-front turns the
// re-read into L3 hits. Non-temporal stores keep `out` from evicting samples;
// non-temporal loads mark consumed lines evict-first.
__global__ __launch_bounds__(256) void norm_kernel(
    const v4f* __restrict__ samples4,
    const int* __restrict__ contexts,
    const float* __restrict__ ws,
    v4f* __restrict__ out4, int n4) {
  __shared__ v4f sc[NCTX * DIM / 4];
  __shared__ v4f sh[NCTX * DIM / 4];
  const v4f* wsc = (const v4f*)(ws + WS_SCALE);
  const v4f* wsh = (const v4f*)(ws + WS_SHIFT);
  for (int i = threadIdx.x; i < NCTX * DIM / 4; i += blockDim.x) {
    sc[i] = wsc[i];
    sh[i] = wsh[i];
  }
  __syncthreads();

  int gid    = blockIdx.x * blockDim.x + threadIdx.x;
  int stride = gridDim.x * blockDim.x;
  if (gid >= n4) return;
  int niter = (n4 - gid + stride - 1) / stride;
  for (int k = niter - 1; k >= 0; --k) {
    int i = k * stride + gid;
    v4f v = __builtin_nontemporal_load(&samples4[i]);
    int row = i >> 4;          // 16 v4f per row (D=64)
    int d4  = i & 15;
    int c   = contexts[row];
    v4f r = v * sc[c * 16 + d4] + sh[c * 16 + d4];
    __builtin_nontemporal_store(r, &out4[i]);
  }
}

extern "C" void kernel_launch(void* const* d_in, const int* in_sizes, int n_in,
                              void* d_out, int out_size, void* d_ws, size_t ws_size,
                              hipStream_t stream) {
  const float* samples  = (const float*)d_in[0];
  const int*   contexts = (const int*)d_in[1];
  const float* gamma    = (const float*)d_in[2];
  const float* beta     = (const float*)d_in[3];
  const float* priors   = (const float*)d_in[4];
  float* out = (float*)d_out;
  float* ws  = (float*)d_ws;

  int N = in_sizes[1];  // contexts has N elements

  // pick partial-block count that fits ws (~17 MB at nb=2048)
  size_t availf = ws_size / sizeof(float);
  int nb = 2048;
  while (nb > 256 &&
         (size_t)WS_PART + (size_t)nb * PART_STRIDE +
         (size_t)NCTX * NSLICE * P2_STRIDE > availf)
    nb >>= 1;

  float* part  = ws + WS_PART;
  float* part2 = part + (size_t)nb * PART_STRIDE;

  stats_kernel<<<nb, 256, 0, stream>>>(samples, contexts, part, N);
  reduce_a_kernel<<<NCTX * NSLICE, 256, 0, stream>>>(part, part2, nb);
  finalize_kernel<<<NCTX, 64, 0, stream>>>(part2, gamma, beta, priors, ws);

  int n4 = N * (DIM / 4);
  norm_kernel<<<4096, 256, 0, stream>>>((const v4f*)samples, contexts, ws,
                                        (v4f*)out, n4);
}

// Round 6
// 296.355 us; speedup vs baseline: 2.4886x; 2.4886x over previous
//
#include <hip/hip_runtime.h>

#define EPSV 0.001f
#define NCTX 16
#define DIM  64
#define NSLICE 16
#define PART_STRIDE 2080   // floats per partial block: s1[1024] s2[1024] cnt[16] pad
#define P2_STRIDE   132    // per (ctx,slice): s1[64] s2[64] cnt[1] pad

// ws layout (floats): [0,1024) scale; [1024,2048) shift;
// [2048, 2048+nb*PART_STRIDE) stage-1 partials; then 16*16*P2_STRIDE stage-2.
#define WS_SCALE 0
#define WS_SHIFT 1024
#define WS_PART  2048

typedef float v4f __attribute__((ext_vector_type(4)));

// ---------------- Pass 1: pure-register one-hot accumulation ----------------
// MEASURED (r1,r5): LDS fp atomics = CAS storm (645us). LDS RMW chains ~100us
// (r3/r4). So: NO LDS in the hot loop. Lane layout: 16 lanes x float4 span a
// row's 64 dims; wave processes 4 rows/pass (1KB coalesced loads). Per ctx k
// (unrolled, compile-time index): oh=(c==k) -> 2 v4f FMAs. ~176 VALU / 4 rows
// -> ~36us total, under the 41us memory floor. Counts: lane with sub==c.
__global__ __launch_bounds__(256) void stats_kernel(
    const float* __restrict__ samples,
    const int* __restrict__ contexts,
    float* __restrict__ part, int N) {
  int tid  = threadIdx.x;
  int lane = tid & 63;
  int wv   = tid >> 6;
  int sub  = lane & 15;   // dim quad: dims [4*sub, 4*sub+4)
  int g    = lane >> 4;   // row slot within a wave pass

  v4f a1[NCTX], a2[NCTX];
#pragma unroll
  for (int k = 0; k < NCTX; ++k) {
    a1[k] = (v4f){0.f, 0.f, 0.f, 0.f};
    a2[k] = (v4f){0.f, 0.f, 0.f, 0.f};
  }
  float cnl = 0.f;   // lane sub counts rows with c==sub (per its g rows)

  const v4f* s4 = (const v4f*)samples;
  int gwave = blockIdx.x * 4 + wv;
  int nwave = gridDim.x * 4;
  int step  = nwave * 4;          // rows consumed per pass across whole grid

#define STLOAD(vv, cc, pbase)                                              \
  do {                                                                     \
    int r_ = (pbase) + g;                                                  \
    if (r_ < N) { vv = s4[(size_t)r_ * 16 + sub]; cc = contexts[r_]; }     \
    else { vv = (v4f){0.f, 0.f, 0.f, 0.f}; cc = -1; }                      \
  } while (0)

#define STPROC(vv, cc)                                                     \
  do {                                                                     \
    v4f vsq_ = (vv) * (vv);                                                \
    _Pragma("unroll")                                                      \
    for (int k = 0; k < NCTX; ++k) {                                       \
      float oh_ = ((cc) == k) ? 1.f : 0.f;                                 \
      v4f ohv_ = {oh_, oh_, oh_, oh_};                                     \
      a1[k] += (vv) * ohv_;                                                \
      a2[k] += vsq_ * ohv_;                                                \
    }                                                                      \
    cnl += ((cc) == sub) ? 1.f : 0.f;                                      \
  } while (0)

  // 2-deep software pipeline over passes (4 rows per wave per pass)
  int pb0 = gwave * 4;
  v4f v0, v1;
  int c0, c1;
  STLOAD(v0, c0, pb0);
  STLOAD(v1, c1, pb0 + step);
  for (int p = pb0; p < N; p += step) {
    v4f vn; int cn2;
    STLOAD(vn, cn2, p + 2 * step);
    STPROC(v0, c0);
    v0 = v1; c0 = c1;
    v1 = vn; c1 = cn2;
  }
#undef STLOAD
#undef STPROC

  // reduce across the 4 row-slots g (lane bits 4,5)
#pragma unroll
  for (int k = 0; k < NCTX; ++k) {
#pragma unroll
    for (int j = 0; j < 4; ++j) {
      a1[k][j] += __shfl_xor(a1[k][j], 16, 64);
      a1[k][j] += __shfl_xor(a1[k][j], 32, 64);
      a2[k][j] += __shfl_xor(a2[k][j], 16, 64);
      a2[k][j] += __shfl_xor(a2[k][j], 32, 64);
    }
  }
  cnl += __shfl_xor(cnl, 16, 64);
  cnl += __shfl_xor(cnl, 32, 64);

  // stage per-wave partials in LDS, block-reduce, write to part
  __shared__ v4f red4[4][NCTX * 16];   // 16 KB
  __shared__ float cshare[4][NCTX];
  float* pb = part + (size_t)blockIdx.x * PART_STRIDE;
  v4f* pb4 = (v4f*)pb;

  if (g == 0) {
#pragma unroll
    for (int k = 0; k < NCTX; ++k) red4[wv][k * 16 + sub] = a1[k];
    cshare[wv][sub] = cnl;
  }
  __syncthreads();
  for (int i = tid; i < NCTX * 16; i += 256)
    pb4[i] = red4[0][i] + red4[1][i] + red4[2][i] + red4[3][i];
  if (tid < NCTX)
    pb[2048 + tid] = cshare[0][tid] + cshare[1][tid] +
                     cshare[2][tid] + cshare[3][tid];
  __syncthreads();
  if (g == 0) {
#pragma unroll
    for (int k = 0; k < NCTX; ++k) red4[wv][k * 16 + sub] = a2[k];
  }
  __syncthreads();
  for (int i = tid; i < NCTX * 16; i += 256)
    pb4[256 + i] = red4[0][i] + red4[1][i] + red4[2][i] + red4[3][i];
}

// ------------- Pass 2a: tree-reduce partials (all CUs active) -------------
__global__ __launch_bounds__(256) void reduce_a_kernel(
    const float* __restrict__ part, float* __restrict__ part2, int nb) {
  int c     = blockIdx.x & (NCTX - 1);
  int slice = blockIdx.x >> 4;
  int tid = threadIdx.x, d = tid & 63, g = tid >> 6;
  int per = nb / NSLICE;
  int b0  = slice * per;

  float a1 = 0.f, a2 = 0.f, ac = 0.f;
  float b1 = 0.f, b2 = 0.f, bc = 0.f;
  for (int b = b0 + g; b < b0 + per; b += 8) {
    const float* p = part + (size_t)b * PART_STRIDE;
    a1 += p[c * DIM + d];
    a2 += p[1024 + c * DIM + d];
    if (d == 0) ac += p[2048 + c];
    int bb = b + 4;
    if (bb < b0 + per) {
      const float* q = part + (size_t)bb * PART_STRIDE;
      b1 += q[c * DIM + d];
      b2 += q[1024 + c * DIM + d];
      if (d == 0) bc += q[2048 + c];
    }
  }
  a1 += b1; a2 += b2; ac += bc;

  __shared__ float r1[4][DIM], r2[4][DIM], rc[4];
  r1[g][d] = a1;
  r2[g][d] = a2;
  if (d == 0) rc[g] = ac;
  __syncthreads();

  if (tid < DIM) {
    float* o = part2 + (size_t)(c * NSLICE + slice) * P2_STRIDE;
    o[tid]      = r1[0][tid] + r1[1][tid] + r1[2][tid] + r1[3][tid];
    o[64 + tid] = r2[0][tid] + r2[1][tid] + r2[2][tid] + r2[3][tid];
    if (tid == 0) o[128] = rc[0] + rc[1] + rc[2] + rc[3];
  }
}

// ------------- Pass 2b: final 16-way sum + scale/shift finalize -------------
__global__ __launch_bounds__(64) void finalize_kernel(
    const float* __restrict__ part2,
    const float* __restrict__ gamma,
    const float* __restrict__ beta,
    const float* __restrict__ priors,
    float* __restrict__ ws) {
  int c = blockIdx.x;
  int d = threadIdx.x;
  float s1 = 0.f, s2 = 0.f, cnt = 0.f;
#pragma unroll
  for (int s = 0; s < NSLICE; ++s) {
    const float* p = part2 + (size_t)(c * NSLICE + s) * P2_STRIDE;
    s1  += p[d];
    s2  += p[64 + d];
    cnt += p[128];
  }
  float safe = fmaxf(cnt, 1.f);
  float mean = s1 / safe;
  float var  = s2 / safe - mean * mean;
  float istd = rsqrtf(var + EPSV);
  float ps   = rsqrtf(priors[c]);
  float gm   = gamma[c * DIM + d];
  float scale = gm * istd * ps;
  float shift = (beta[c * DIM + d] - gm * mean * istd) * ps;
  if (!(cnt > 0.f)) { scale = 1.f; shift = 0.f; }  // where(cnt>0, y, x)
  ws[WS_SCALE + c * DIM + d] = scale;
  ws[WS_SHIFT + c * DIM + d] = shift;
}

// ---------------- Pass 3: y = x * scale[c] + shift[c] ----------------
// Reverse traversal (tail of samples is L3-resident after stats) +
// non-temporal loads/stores to avoid polluting L3 with dead lines.
__global__ __launch_bounds__(256) void norm_kernel(
    const v4f* __restrict__ samples4,
    const int* __restrict__ contexts,
    const float* __restrict__ ws,
    v4f* __restrict__ out4, int n4) {
  __shared__ v4f sc[NCTX * DIM / 4];
  __shared__ v4f sh[NCTX * DIM / 4];
  const v4f* wsc = (const v4f*)(ws + WS_SCALE);
  const v4f* wsh = (const v4f*)(ws + WS_SHIFT);
  for (int i = threadIdx.x; i < NCTX * DIM / 4; i += blockDim.x) {
    sc[i] = wsc[i];
    sh[i] = wsh[i];
  }
  __syncthreads();

  int gid    = blockIdx.x * blockDim.x + threadIdx.x;
  int stride = gridDim.x * blockDim.x;
  if (gid >= n4) return;
  int niter = (n4 - gid + stride - 1) / stride;
  for (int k = niter - 1; k >= 0; --k) {
    int i = k * stride + gid;
    v4f v = __builtin_nontemporal_load(&samples4[i]);
    int row = i >> 4;          // 16 v4f per row (D=64)
    int d4  = i & 15;
    int c   = contexts[row];
    v4f r = v * sc[c * 16 + d4] + sh[c * 16 + d4];
    __builtin_nontemporal_store(r, &out4[i]);
  }
}

extern "C" void kernel_launch(void* const* d_in, const int* in_sizes, int n_in,
                              void* d_out, int out_size, void* d_ws, size_t ws_size,
                              hipStream_t stream) {
  const float* samples  = (const float*)d_in[0];
  const int*   contexts = (const int*)d_in[1];
  const float* gamma    = (const float*)d_in[2];
  const float* beta     = (const float*)d_in[3];
  const float* priors   = (const float*)d_in[4];
  float* out = (float*)d_out;
  float* ws  = (float*)d_ws;

  int N = in_sizes[1];  // contexts has N elements

  // pick partial-block count that fits ws (~17 MB at nb=2048)
  size_t availf = ws_size / sizeof(float);
  int nb = 2048;
  while (nb > 256 &&
         (size_t)WS_PART + (size_t)nb * PART_STRIDE +
         (size_t)NCTX * NSLICE * P2_STRIDE > availf)
    nb >>= 1;

  float* part  = ws + WS_PART;
  float* part2 = part + (size_t)nb * PART_STRIDE;

  stats_kernel<<<nb, 256, 0, stream>>>(samples, contexts, part, N);
  reduce_a_kernel<<<NCTX * NSLICE, 256, 0, stream>>>(part, part2, nb);
  finalize_kernel<<<NCTX, 64, 0, stream>>>(part2, gamma, beta, priors, ws);

  int n4 = N * (DIM / 4);
  norm_kernel<<<4096, 256, 0, stream>>>((const v4f*)samples, contexts, ws,
                                        (v4f*)out, n4);
}

// Round 7
// 140.008 us; speedup vs baseline: 5.2676x; 2.1167x over previous
//
#include <hip/hip_runtime.h>

#define EPSV 0.001f
#define NCTX 16
#define DIM  64
#define NSLICE 16
#define PART_STRIDE 2080   // floats per partial block: s1[1024] s2[1024] cnt[16] pad
#define P2_STRIDE   132    // per (ctx,slice): s1[64] s2[64] cnt[1] pad

// ws layout (floats): [0,1024) scale; [1024,2048) shift;
// [2048, 2048+nb*PART_STRIDE) stage-1 partials; then 16*16*P2_STRIDE stage-2.
#define WS_SCALE 0
#define WS_SHIFT 1024
#define WS_PART  2048

#define STATS_BLOCKS 1024   // 4 waves/block -> 4096 waves, 4 blocks/CU (LDS-capped)

typedef float v4f __attribute__((ext_vector_type(4)));

// ---------------- Pass 1: private-LDS RMW + chunked batched loads ----------------
// MEASURED so far: global fp CAS 650us (r1), LDS fp CAS 645us (r5), scalar-branch
// switch ~95us (r2), LDS RMW + rotating guarded pipeline ~100us (r3/r4, MLP
// defeated), register one-hot 236us (r6, VALU x16 + VGPR>128 occupancy cliff).
// This version: r3's collision-free one-row-per-pass ds_read_b64/ds_write_b64 RMW
// (float2{s1,s2}, per-wave private 8KB, in-wave DS ordering = correct, no atomics)
// + contiguous per-wave rows with straight-line chunk-of-8 loads (clamped addr,
// weight-neutralized tail, NO branches) so the compiler batches 8 loads and uses
// counted vmcnt -> real MLP. ctx loads are wave-uniform -> SMEM.
__global__ __launch_bounds__(256) void stats_kernel(
    const float* __restrict__ samples,
    const int* __restrict__ contexts,
    float* __restrict__ part, int N, int rpw) {
  __shared__ float2 sacc2[4][NCTX * DIM];   // 32 KB: per-wave {s1,s2}
  __shared__ float  cshare[4][NCTX];

  int tid  = threadIdx.x;
  int lane = tid & 63;
  int wv   = tid >> 6;

  float2* zz = &sacc2[0][0];
  for (int i = tid; i < 4 * NCTX * DIM; i += 256) zz[i] = make_float2(0.f, 0.f);
  __syncthreads();

  float2* m = sacc2[wv];
  float cnl = 0.f;   // lane L counts rows with c==L (L<16 meaningful)

  int wid   = blockIdx.x * 4 + wv;
  int start = wid * rpw;
  int end   = min(N, start + rpw);

  for (int base = start; base < end; base += 8) {
    float vv[8]; int cc[8]; float wt[8];
#pragma unroll
    for (int p = 0; p < 8; ++p) {
      int r  = base + p;
      int rc = min(r, N - 1);
      vv[p] = samples[(size_t)rc * DIM + lane];
      cc[p] = contexts[rc];                  // wave-uniform address
      wt[p] = (r < end) ? 1.f : 0.f;         // tail/overlap neutralizer
    }
#pragma unroll
    for (int p = 0; p < 8; ++p) {
      int   cp = cc[p];
      float w  = wt[p];
      float v  = vv[p];
      float vw = v * w;
      float2 t = m[cp * DIM + lane];
      t.x += vw;                     // s1 += v (or 0)
      t.y = fmaf(vw, v, t.y);        // s2 += v*v (or 0)
      m[cp * DIM + lane] = t;
      cnl += (lane == cp) ? w : 0.f;
    }
  }

  __syncthreads();

  // block-reduce the 4 per-wave regions, write partials in old layout
  float* pb = part + (size_t)blockIdx.x * PART_STRIDE;
  for (int i = tid; i < NCTX * DIM; i += 256) {
    float2 a0 = sacc2[0][i];
    float2 a1 = sacc2[1][i];
    float2 a2 = sacc2[2][i];
    float2 a3 = sacc2[3][i];
    pb[i]        = a0.x + a1.x + a2.x + a3.x;
    pb[1024 + i] = a0.y + a1.y + a2.y + a3.y;
  }
  if (lane < NCTX) cshare[wv][lane] = cnl;
  __syncthreads();
  if (tid < NCTX)
    pb[2048 + tid] = cshare[0][tid] + cshare[1][tid] +
                     cshare[2][tid] + cshare[3][tid];
}

// ------------- Pass 2a: tree-reduce partials (all CUs active) -------------
__global__ __launch_bounds__(256) void reduce_a_kernel(
    const float* __restrict__ part, float* __restrict__ part2, int nb) {
  int c     = blockIdx.x & (NCTX - 1);
  int slice = blockIdx.x >> 4;
  int tid = threadIdx.x, d = tid & 63, g = tid >> 6;
  int per = nb / NSLICE;
  int b0  = slice * per;

  float a1 = 0.f, a2 = 0.f, ac = 0.f;
  float b1 = 0.f, b2 = 0.f, bc = 0.f;
  for (int b = b0 + g; b < b0 + per; b += 8) {
    const float* p = part + (size_t)b * PART_STRIDE;
    a1 += p[c * DIM + d];
    a2 += p[1024 + c * DIM + d];
    if (d == 0) ac += p[2048 + c];
    int bb = b + 4;
    if (bb < b0 + per) {
      const float* q = part + (size_t)bb * PART_STRIDE;
      b1 += q[c * DIM + d];
      b2 += q[1024 + c * DIM + d];
      if (d == 0) bc += q[2048 + c];
    }
  }
  a1 += b1; a2 += b2; ac += bc;

  __shared__ float r1[4][DIM], r2[4][DIM], rc[4];
  r1[g][d] = a1;
  r2[g][d] = a2;
  if (d == 0) rc[g] = ac;
  __syncthreads();

  if (tid < DIM) {
    float* o = part2 + (size_t)(c * NSLICE + slice) * P2_STRIDE;
    o[tid]      = r1[0][tid] + r1[1][tid] + r1[2][tid] + r1[3][tid];
    o[64 + tid] = r2[0][tid] + r2[1][tid] + r2[2][tid] + r2[3][tid];
    if (tid == 0) o[128] = rc[0] + rc[1] + rc[2] + rc[3];
  }
}

// ------------- Pass 2b: final 16-way sum + scale/shift finalize -------------
__global__ __launch_bounds__(64) void finalize_kernel(
    const float* __restrict__ part2,
    const float* __restrict__ gamma,
    const float* __restrict__ beta,
    const float* __restrict__ priors,
    float* __restrict__ ws) {
  int c = blockIdx.x;
  int d = threadIdx.x;
  float s1 = 0.f, s2 = 0.f, cnt = 0.f;
#pragma unroll
  for (int s = 0; s < NSLICE; ++s) {
    const float* p = part2 + (size_t)(c * NSLICE + s) * P2_STRIDE;
    s1  += p[d];
    s2  += p[64 + d];
    cnt += p[128];
  }
  float safe = fmaxf(cnt, 1.f);
  float mean = s1 / safe;
  float var  = s2 / safe - mean * mean;
  float istd = rsqrtf(var + EPSV);
  float ps   = rsqrtf(priors[c]);
  float gm   = gamma[c * DIM + d];
  float scale = gm * istd * ps;
  float shift = (beta[c * DIM + d] - gm * mean * istd) * ps;
  if (!(cnt > 0.f)) { scale = 1.f; shift = 0.f; }  // where(cnt>0, y, x)
  ws[WS_SCALE + c * DIM + d] = scale;
  ws[WS_SHIFT + c * DIM + d] = shift;
}

// ---------------- Pass 3: y = x * scale[c] + shift[c] ----------------
// Reverse traversal (tail of samples is L3-resident after stats) +
// non-temporal loads/stores to avoid polluting L3 with dead lines.
__global__ __launch_bounds__(256) void norm_kernel(
    const v4f* __restrict__ samples4,
    const int* __restrict__ contexts,
    const float* __restrict__ ws,
    v4f* __restrict__ out4, int n4) {
  __shared__ v4f sc[NCTX * DIM / 4];
  __shared__ v4f sh[NCTX * DIM / 4];
  const v4f* wsc = (const v4f*)(ws + WS_SCALE);
  const v4f* wsh = (const v4f*)(ws + WS_SHIFT);
  for (int i = threadIdx.x; i < NCTX * DIM / 4; i += blockDim.x) {
    sc[i] = wsc[i];
    sh[i] = wsh[i];
  }
  __syncthreads();

  int gid    = blockIdx.x * blockDim.x + threadIdx.x;
  int stride = gridDim.x * blockDim.x;
  if (gid >= n4) return;
  int niter = (n4 - gid + stride - 1) / stride;
  for (int k = niter - 1; k >= 0; --k) {
    int i = k * stride + gid;
    v4f v = __builtin_nontemporal_load(&samples4[i]);
    int row = i >> 4;          // 16 v4f per row (D=64)
    int d4  = i & 15;
    int c   = contexts[row];
    v4f r = v * sc[c * 16 + d4] + sh[c * 16 + d4];
    __builtin_nontemporal_store(r, &out4[i]);
  }
}

extern "C" void kernel_launch(void* const* d_in, const int* in_sizes, int n_in,
                              void* d_out, int out_size, void* d_ws, size_t ws_size,
                              hipStream_t stream) {
  const float* samples  = (const float*)d_in[0];
  const int*   contexts = (const int*)d_in[1];
  const float* gamma    = (const float*)d_in[2];
  const float* beta     = (const float*)d_in[3];
  const float* priors   = (const float*)d_in[4];
  float* out = (float*)d_out;
  float* ws  = (float*)d_ws;

  int N = in_sizes[1];  // contexts has N elements

  int nb = STATS_BLOCKS;
  // rows per wave: ceil(N / 4096) rounded up to chunk size 8
  int nwaves = nb * 4;
  int rpw = ((N + nwaves - 1) / nwaves + 7) & ~7;

  float* part  = ws + WS_PART;
  float* part2 = part + (size_t)nb * PART_STRIDE;

  stats_kernel<<<nb, 256, 0, stream>>>(samples, contexts, part, N, rpw);
  reduce_a_kernel<<<NCTX * NSLICE, 256, 0, stream>>>(part, part2, nb);
  finalize_kernel<<<NCTX, 64, 0, stream>>>(part2, gamma, beta, priors, ws);

  int n4 = N * (DIM / 4);
  norm_kernel<<<4096, 256, 0, stream>>>((const v4f*)samples, contexts, ws,
                                        (v4f*)out, n4);
}